// Round 1
// baseline (361.071 us; speedup 1.0000x reference)
//
#include <hip/hip_runtime.h>
#include <hip/hip_bf16.h>

#define BN 32
#define NPTS 400000
#define NVOX 2560
#define GDYZ 160
#define GDZ 10
#define VN 60
#define PMAX 40
#define CAP 512
#define CHUNKS_PER_B 8
#define CHUNK (NPTS / CHUNKS_PER_B)  /* 50000 */

/* ws layout (bytes) */
#define OFF_COUNTS 0
#define SZ_COUNTS (BN * NVOX * 4)                 /* 327680 */
#define OFF_TICKETS (OFF_COUNTS + SZ_COUNTS)
#define SZ_TICKETS (BN * VN * 4)                  /* 7680 */
#define OFF_TOPVOX (OFF_TICKETS + SZ_TICKETS)
#define OFF_TOPCNT (OFF_TOPVOX + BN * VN * 4)
#define OFF_SLOTMAP (OFF_TOPCNT + BN * VN * 4)
#define OFF_LISTS (OFF_SLOTMAP + BN * NVOX)
#define SZ_LISTS (BN * VN * CAP * 4)              /* 3932160 */
#define OFF_VOX (OFF_LISTS + SZ_LISTS)
#define SZ_VOX (BN * NPTS * 2)                    /* 25.6 MB */

/* out layout (floats) */
#define OUT_PTS 0
#define OUT_VL (BN * VN * PMAX * 3)   /* 230400 */
#define OUT_KC (OUT_VL + BN * VN * 3) /* 236160 */

__device__ __constant__ float KENC[17][5] = {
    {0,0,0,0,1},{0,0,0,1,0},{0,0,0,1,1},{0,0,1,0,0},{0,0,1,0,1},{0,0,1,1,0},
    {0,0,1,1,1},{0,1,0,0,0},{0,1,0,0,1},{0,1,0,1,0},{0,1,0,1,1},{0,1,1,0,0},
    {0,1,1,0,1},{0,1,1,1,0},{0,1,1,1,1},{1,0,0,0,0},{1,0,0,0,1}};

// Exact replica of reference voxelization:
//   vl = ((p - lo)/0.4).astype(int32)  (IEEE f32 sub+div, truncate toward 0)
//   invalid if p == (0,0,0); out-of-range -> sentinel 0xFFFF
__device__ __forceinline__ int voxid(float x, float y, float z) {
    float ex = x;                        // x - 0.0f == x (also for -0.0)
    float ey = __fadd_rn(y, 3.2f);       // y - (-3.2f)
    float ez = __fadd_rn(z, 2.0f);       // z - (-2.0f)
    int vx = (int)(ex / 0.4f);
    int vy = (int)(ey / 0.4f);
    int vz = (int)(ez / 0.4f);
    bool valid = !(x == 0.0f && y == 0.0f && z == 0.0f);
    bool inr = (vx >= 0) & (vx < 16) & (vy >= 0) & (vy < 16) & (vz >= 0) & (vz < 10);
    return (valid && inr) ? (vx * GDYZ + vy * GDZ + vz) : 0xFFFF;
}

__global__ __launch_bounds__(256) void k_vox_hist(const float* __restrict__ pc,
        unsigned int* __restrict__ counts, unsigned short* __restrict__ vox, int useVox) {
    __shared__ unsigned int hist[NVOX];
    int b = blockIdx.x / CHUNKS_PER_B;
    int ch = blockIdx.x % CHUNKS_PER_B;
    for (int v = threadIdx.x; v < NVOX; v += 256) hist[v] = 0u;
    __syncthreads();
    const float4* p4 = (const float4*)(pc + (size_t)b * NPTS * 3);
    int start = ch * CHUNK, end = start + CHUNK;
    for (int g = start + threadIdx.x * 4; g < end; g += 256 * 4) {
        int f = (g * 3) >> 2;  // g multiple of 4 -> exact
        float4 q0 = p4[f], q1 = p4[f + 1], q2 = p4[f + 2];
        float xs[4] = {q0.x, q0.w, q1.z, q2.y};
        float ys[4] = {q0.y, q1.x, q1.w, q2.z};
        float zs[4] = {q0.z, q1.y, q2.x, q2.w};
#pragma unroll
        for (int k = 0; k < 4; ++k) {
            int id = voxid(xs[k], ys[k], zs[k]);
            if (useVox) vox[(size_t)b * NPTS + g + k] = (unsigned short)id;
            if (id < NVOX) atomicAdd(&hist[id], 1u);
        }
    }
    __syncthreads();
    for (int v = threadIdx.x; v < NVOX; v += 256) {
        unsigned int c = hist[v];
        if (c) atomicAdd(&counts[b * NVOX + v], c);
    }
}

// Per-batch top-60 by (count desc, index asc) == jax.lax.top_k order.
__global__ __launch_bounds__(256) void k_topk(const unsigned int* __restrict__ counts,
        int* __restrict__ topvox, int* __restrict__ topcnt,
        unsigned char* __restrict__ slotmap, float* __restrict__ out) {
    __shared__ unsigned int keys[NVOX];
    __shared__ unsigned int red[256];
    int b = blockIdx.x;
    for (int v = threadIdx.x; v < NVOX; v += 256) {
        keys[v] = (counts[b * NVOX + v] << 12) | (unsigned int)(4095 - v);
        slotmap[b * NVOX + v] = 0xFF;
    }
    __syncthreads();
    for (int r = 0; r < VN; ++r) {
        unsigned int m = 0u;
        for (int v = threadIdx.x; v < NVOX; v += 256) {
            unsigned int k = keys[v];
            m = (k > m) ? k : m;
        }
        red[threadIdx.x] = m;
        __syncthreads();
        for (int s = 128; s > 0; s >>= 1) {
            if (threadIdx.x < s) {
                unsigned int a = red[threadIdx.x], bb = red[threadIdx.x + s];
                red[threadIdx.x] = (bb > a) ? bb : a;
            }
            __syncthreads();
        }
        if (threadIdx.x == 0) {
            unsigned int best = red[0];
            int v = 4095 - (int)(best & 4095u);
            topvox[b * VN + r] = v;
            topcnt[b * VN + r] = (int)(best >> 12);
            slotmap[b * NVOX + v] = (unsigned char)r;
            keys[v] = 0u;  // selected keys can never win again
        }
        __syncthreads();
    }
    if (threadIdx.x < VN) {
        int v = topvox[b * VN + threadIdx.x];
        int vx = v / GDYZ, rem = v % GDYZ, vy = rem / GDZ, vz = rem % GDZ;
        // lo + vox*0.4 + 0.2, left-assoc, no FMA contraction (match numpy)
        float c0 = __fadd_rn(__fmul_rn((float)vx, 0.4f), 0.2f);  // lo=0
        float c1 = __fadd_rn(__fadd_rn(-3.2f, __fmul_rn((float)vy, 0.4f)), 0.2f);
        float c2 = __fadd_rn(__fadd_rn(-2.0f, __fmul_rn((float)vz, 0.4f)), 0.2f);
        float* vl = out + OUT_VL + (b * VN + threadIdx.x) * 3;
        vl[0] = c0; vl[1] = c1; vl[2] = c2;
    }
}

__global__ __launch_bounds__(256) void k_build_lists(const float* __restrict__ pc,
        const unsigned short* __restrict__ vox, int useVox,
        const unsigned char* __restrict__ slotmap,
        unsigned int* __restrict__ tickets, unsigned int* __restrict__ lists) {
    __shared__ unsigned char smap[NVOX];
    int b = blockIdx.x / CHUNKS_PER_B;
    int ch = blockIdx.x % CHUNKS_PER_B;
    for (int v = threadIdx.x; v < NVOX; v += 256) smap[v] = slotmap[b * NVOX + v];
    __syncthreads();
    int start = ch * CHUNK, end = start + CHUNK;
    if (useVox) {
        const unsigned short* vb = vox + (size_t)b * NPTS;
        for (int i = start + threadIdx.x; i < end; i += 256) {
            int id = vb[i];
            if (id < NVOX) {
                unsigned char s = smap[id];
                if (s != 0xFF) {
                    unsigned int t = atomicAdd(&tickets[b * VN + s], 1u);
                    if (t < CAP) lists[(size_t)(b * VN + s) * CAP + t] = (unsigned int)i;
                }
            }
        }
    } else {
        const float* pb = pc + (size_t)b * NPTS * 3;
        for (int i = start + threadIdx.x; i < end; i += 256) {
            int id = voxid(pb[i * 3], pb[i * 3 + 1], pb[i * 3 + 2]);
            if (id < NVOX) {
                unsigned char s = smap[id];
                if (s != 0xFF) {
                    unsigned int t = atomicAdd(&tickets[b * VN + s], 1u);
                    if (t < CAP) lists[(size_t)(b * VN + s) * CAP + t] = (unsigned int)i;
                }
            }
        }
    }
}

// One wave per (batch, slot): pick the 40 smallest point indices (== stable
// argsort "first 40"), handle cnt<40 cycling (j % cnt), gather points.
__global__ __launch_bounds__(64) void k_select_gather(const float* __restrict__ pc,
        const int* __restrict__ topvox, const int* __restrict__ topcnt,
        const unsigned int* __restrict__ lists, float* __restrict__ out) {
    __shared__ unsigned int sorted[PMAX];
    int bs = blockIdx.x;
    int b = bs / VN;
    int lane = threadIdx.x;
    int cnt = topcnt[bs];
    float* po = out + OUT_PTS + (size_t)bs * PMAX * 3;
    if (cnt == 0) {  // empty voxel selected (cannot happen with this data)
        for (int t = lane; t < PMAX * 3; t += 64) po[t] = 0.0f;
        return;
    }
    int K = cnt < PMAX ? cnt : PMAX;
    if (cnt <= CAP) {
        const unsigned int* L = lists + (size_t)bs * CAP;
        unsigned int vals[CAP / 64];
#pragma unroll
        for (int q = 0; q < CAP / 64; ++q) {
            int e = lane + q * 64;
            vals[q] = (e < cnt) ? L[e] : 0xFFFFFFFFu;
        }
        unsigned int lastp = 0u;
        for (int r = 0; r < K; ++r) {
            unsigned int m = 0xFFFFFFFFu;
#pragma unroll
            for (int q = 0; q < CAP / 64; ++q) {
                unsigned int v = vals[q];
                if (v >= lastp && v < m) m = v;
            }
#pragma unroll
            for (int o = 32; o > 0; o >>= 1) {
                unsigned int t = __shfl_xor(m, o, 64);
                m = (t < m) ? t : m;
            }
            if (lane == 0) sorted[r] = m;
            lastp = m + 1u;
        }
    } else {
        // cnt > CAP: ordered single-wave scan of the whole batch (rare path)
        const float* pb = pc + (size_t)b * NPTS * 3;
        int v = topvox[bs];
        int k = 0;
        for (int base = 0; base < NPTS && k < PMAX; base += 64) {
            int i = base + lane;
            int id = voxid(pb[i * 3], pb[i * 3 + 1], pb[i * 3 + 2]);
            unsigned long long mask = __ballot(id == v);
            if (id == v) {
                int rk = k + (int)__popcll(mask & ((1ull << lane) - 1ull));
                if (rk < PMAX) sorted[rk] = (unsigned int)i;
            }
            k += (int)__popcll(mask);
        }
    }
    __syncthreads();
    for (int t = lane; t < PMAX * 3; t += 64) {
        int j = t / 3, kk = t % 3;
        int jj = (cnt >= PMAX) ? j : (j % cnt);
        unsigned int idx = sorted[jj];
        po[t] = pc[((size_t)b * NPTS + idx) * 3 + kk];
    }
}

// Keypoint conditioning: 1 thread per batch (tiny). Exact f32, no FMA,
// strict-< argmin (first occurrence), sequential 17-step update.
__global__ __launch_bounds__(64) void k_kc(const float* __restrict__ kpts,
                                           float* __restrict__ out) {
    int b = threadIdx.x;
    if (b >= BN) return;
    float* kc = out + OUT_KC + b * VN * 6;
    for (int i = 0; i < VN * 6; ++i) kc[i] = 0.0f;
    const float* vl = out + OUT_VL + b * VN * 3;
    const float* kp = kpts + b * 17 * 3;
    for (int j = 0; j < 17; ++j) {
        // kq = kpts[:, [2,0,1]]
        float a0 = kp[j * 3 + 2], a1 = kp[j * 3 + 0], a2 = kp[j * 3 + 1];
        float best = 1e30f;
        int bi = 0;
        for (int i = 0; i < VN; ++i) {
            float d0 = __fsub_rn(a0, vl[i * 3 + 0]);
            float d1 = __fsub_rn(a1, vl[i * 3 + 1]);
            float d2 = __fsub_rn(a2, vl[i * 3 + 2]);
            float sq = __fadd_rn(__fadd_rn(__fmul_rn(d0, d0), __fmul_rn(d1, d1)),
                                 __fmul_rn(d2, d2));
            float d = __fsqrt_rn(sq);
            if (d < best) { best = d; bi = i; }
        }
        float e[6] = {KENC[j][0], KENC[j][1], KENC[j][2], KENC[j][3], KENC[j][4], best};
        float* row = kc + bi * 6;
        bool z = true;
        for (int q = 0; q < 6; ++q) z = z && (row[q] == 0.0f);
        for (int q = 0; q < 6; ++q)
            row[q] = z ? e[q] : __fmul_rn(__fadd_rn(row[q], e[q]), 0.5f);
    }
}

extern "C" void kernel_launch(void* const* d_in, const int* in_sizes, int n_in,
                              void* d_out, int out_size, void* d_ws, size_t ws_size,
                              hipStream_t stream) {
    const float* pc = (const float*)d_in[0];
    const float* kpts = (const float*)d_in[1];
    float* out = (float*)d_out;
    char* ws = (char*)d_ws;

    unsigned int* counts = (unsigned int*)(ws + OFF_COUNTS);
    unsigned int* tickets = (unsigned int*)(ws + OFF_TICKETS);
    int* topvox = (int*)(ws + OFF_TOPVOX);
    int* topcnt = (int*)(ws + OFF_TOPCNT);
    unsigned char* slotmap = (unsigned char*)(ws + OFF_SLOTMAP);
    unsigned int* lists = (unsigned int*)(ws + OFF_LISTS);
    unsigned short* vox = (unsigned short*)(ws + OFF_VOX);
    int useVox = (ws_size >= (size_t)(OFF_VOX + SZ_VOX)) ? 1 : 0;

    hipMemsetAsync(ws + OFF_COUNTS, 0, SZ_COUNTS + SZ_TICKETS, stream);
    hipLaunchKernelGGL(k_vox_hist, dim3(BN * CHUNKS_PER_B), dim3(256), 0, stream,
                       pc, counts, vox, useVox);
    hipLaunchKernelGGL(k_topk, dim3(BN), dim3(256), 0, stream,
                       counts, topvox, topcnt, slotmap, out);
    hipLaunchKernelGGL(k_build_lists, dim3(BN * CHUNKS_PER_B), dim3(256), 0, stream,
                       pc, vox, useVox, slotmap, tickets, lists);
    hipLaunchKernelGGL(k_select_gather, dim3(BN * VN), dim3(64), 0, stream,
                       pc, topvox, topcnt, lists, out);
    hipLaunchKernelGGL(k_kc, dim3(1), dim3(64), 0, stream, kpts, out);
}

// Round 2
// 170.386 us; speedup vs baseline: 2.1191x; 2.1191x over previous
//
#include <hip/hip_runtime.h>
#include <hip/hip_bf16.h>

#define BN 32
#define NPTS 400000
#define NVOX 2560
#define GDYZ 160
#define GDZ 10
#define VN 60
#define PMAX 40
#define CAP 512

/* hist pass geometry */
#define NCH_H 40
#define CHUNK_H (NPTS / NCH_H)   /* 10000, %4 == 0 */
/* list pass geometry */
#define NCH_L 50
#define CHUNK_L (NPTS / NCH_L)   /* 8000, %8 == 0 */

/* ws layout (bytes) */
#define OFF_COUNTS 0
#define SZ_COUNTS (BN * NVOX * 4)                 /* 327680 */
#define OFF_TICKETS (OFF_COUNTS + SZ_COUNTS)
#define SZ_TICKETS (BN * VN * 4)                  /* 7680 */
#define OFF_TOPVOX (OFF_TICKETS + SZ_TICKETS)
#define OFF_TOPCNT (OFF_TOPVOX + BN * VN * 4)
#define OFF_SLOTMAP (OFF_TOPCNT + BN * VN * 4)
#define OFF_LISTS (OFF_SLOTMAP + BN * NVOX)
#define SZ_LISTS (BN * VN * CAP * 4)              /* 3932160 */
#define OFF_VOX (OFF_LISTS + SZ_LISTS)
#define SZ_VOX (BN * NPTS * 2)                    /* 25.6 MB */
#define OFF_PART (OFF_VOX + SZ_VOX)
#define SZ_PART (BN * NCH_H * NVOX * 4)           /* 13.1 MB */

/* out layout (floats) */
#define OUT_PTS 0
#define OUT_VL (BN * VN * PMAX * 3)   /* 230400 */
#define OUT_KC (OUT_VL + BN * VN * 3) /* 236160 */

__device__ __constant__ float KENC[17][5] = {
    {0,0,0,0,1},{0,0,0,1,0},{0,0,0,1,1},{0,0,1,0,0},{0,0,1,0,1},{0,0,1,1,0},
    {0,0,1,1,1},{0,1,0,0,0},{0,1,0,0,1},{0,1,0,1,0},{0,1,0,1,1},{0,1,1,0,0},
    {0,1,1,0,1},{0,1,1,1,0},{0,1,1,1,1},{1,0,0,0,0},{1,0,0,0,1}};

// Exact replica of reference voxelization (IEEE f32 sub + div, trunc).
__device__ __forceinline__ int voxid(float x, float y, float z) {
    float ex = x;
    float ey = __fadd_rn(y, 3.2f);
    float ez = __fadd_rn(z, 2.0f);
    int vx = (int)(ex / 0.4f);
    int vy = (int)(ey / 0.4f);
    int vz = (int)(ez / 0.4f);
    bool valid = !(x == 0.0f && y == 0.0f && z == 0.0f);
    bool inr = (vx >= 0) & (vx < 16) & (vy >= 0) & (vy < 16) & (vz >= 0) & (vz < 10);
    return (valid && inr) ? (vx * GDYZ + vy * GDZ + vz) : 0xFFFF;
}

// Pass 1: voxel-id cache (u16) + per-(batch,chunk) partial histogram.
__global__ __launch_bounds__(256) void k_vox_hist(const float* __restrict__ pc,
        unsigned int* __restrict__ counts, unsigned short* __restrict__ vox,
        unsigned int* __restrict__ partials, int useVox, int usePart) {
    __shared__ unsigned int hist[NVOX];
    int b = blockIdx.x / NCH_H;
    int ch = blockIdx.x % NCH_H;
    for (int v = threadIdx.x; v < NVOX; v += 256) hist[v] = 0u;
    __syncthreads();
    const float4* p4 = (const float4*)(pc + (size_t)b * NPTS * 3);
    int start = ch * CHUNK_H, end = start + CHUNK_H;
    for (int g = start + threadIdx.x * 4; g < end; g += 256 * 4) {
        int f = (g * 3) >> 2;  // g % 4 == 0 -> exact
        float4 q0 = p4[f], q1 = p4[f + 1], q2 = p4[f + 2];
        float xs[4] = {q0.x, q0.w, q1.z, q2.y};
        float ys[4] = {q0.y, q1.x, q1.w, q2.z};
        float zs[4] = {q0.z, q1.y, q2.x, q2.w};
        unsigned short ids[4];
#pragma unroll
        for (int k = 0; k < 4; ++k) {
            int id = voxid(xs[k], ys[k], zs[k]);
            ids[k] = (unsigned short)id;
            if (id < NVOX) atomicAdd(&hist[id], 1u);
        }
        if (useVox) *(ushort2*)(&vox[(size_t)b * NPTS + g]) =
                        make_ushort2((unsigned short)(ids[0] | 0u) , ids[1]),
                    *(ushort2*)(&vox[(size_t)b * NPTS + g + 2]) = make_ushort2(ids[2], ids[3]);
    }
    __syncthreads();
    if (usePart) {
        unsigned int* dst = partials + ((size_t)b * NCH_H + ch) * NVOX;
        for (int v = threadIdx.x; v < NVOX; v += 256) dst[v] = hist[v];
    } else {
        for (int v = threadIdx.x; v < NVOX; v += 256) {
            unsigned int c = hist[v];
            if (c) atomicAdd(&counts[b * NVOX + v], c);
        }
    }
}

// Pass 1b: counts[b][v] = sum over chunks of partials.
__global__ __launch_bounds__(256) void k_reduce_counts(
        const unsigned int* __restrict__ partials, unsigned int* __restrict__ counts) {
    int t = blockIdx.x * 256 + threadIdx.x;
    if (t >= BN * NVOX) return;
    int b = t / NVOX, v = t % NVOX;
    const unsigned int* src = partials + (size_t)b * NCH_H * NVOX + v;
    unsigned int s = 0;
#pragma unroll 8
    for (int c = 0; c < NCH_H; ++c) s += src[(size_t)c * NVOX];
    counts[t] = s;
}

// Per-batch top-60 by (count desc, index asc) == jax.lax.top_k order.
__global__ __launch_bounds__(256) void k_topk(const unsigned int* __restrict__ counts,
        int* __restrict__ topvox, int* __restrict__ topcnt,
        unsigned char* __restrict__ slotmap, float* __restrict__ out) {
    __shared__ unsigned int keys[NVOX];
    __shared__ unsigned int red[4];
    int b = blockIdx.x;
    int tid = threadIdx.x;
    for (int v = tid; v < NVOX; v += 256) {
        keys[v] = (counts[b * NVOX + v] << 12) | (unsigned int)(4095 - v);
        slotmap[b * NVOX + v] = 0xFF;
    }
    __syncthreads();
    for (int r = 0; r < VN; ++r) {
        unsigned int m = 0u;
        for (int v = tid; v < NVOX; v += 256) {
            unsigned int k = keys[v];
            m = (k > m) ? k : m;
        }
#pragma unroll
        for (int o = 32; o > 0; o >>= 1) {
            unsigned int t = __shfl_xor(m, o, 64);
            m = (t > m) ? t : m;
        }
        if ((tid & 63) == 0) red[tid >> 6] = m;
        __syncthreads();
        if (tid == 0) {
            unsigned int best = red[0];
            if (red[1] > best) best = red[1];
            if (red[2] > best) best = red[2];
            if (red[3] > best) best = red[3];
            int v = 4095 - (int)(best & 4095u);
            topvox[b * VN + r] = v;
            topcnt[b * VN + r] = (int)(best >> 12);
            slotmap[b * NVOX + v] = (unsigned char)r;
            keys[v] = 0u;
        }
        __syncthreads();
    }
    if (tid < VN) {
        int v = topvox[b * VN + tid];
        int vx = v / GDYZ, rem = v % GDYZ, vy = rem / GDZ, vz = rem % GDZ;
        float c0 = __fadd_rn(__fmul_rn((float)vx, 0.4f), 0.2f);
        float c1 = __fadd_rn(__fadd_rn(-3.2f, __fmul_rn((float)vy, 0.4f)), 0.2f);
        float c2 = __fadd_rn(__fadd_rn(-2.0f, __fmul_rn((float)vz, 0.4f)), 0.2f);
        float* vl = out + OUT_VL + (b * VN + tid) * 3;
        vl[0] = c0; vl[1] = c1; vl[2] = c2;
    }
}

// Pass 2: for each point in a selected voxel, grab a ticket and record index.
__global__ __launch_bounds__(256) void k_build_lists(const float* __restrict__ pc,
        const unsigned short* __restrict__ vox, int useVox,
        const unsigned char* __restrict__ slotmap,
        unsigned int* __restrict__ tickets, unsigned int* __restrict__ lists) {
    __shared__ unsigned char smap[NVOX];
    int b = blockIdx.x / NCH_L;
    int ch = blockIdx.x % NCH_L;
    {
        const unsigned int* s32 = (const unsigned int*)(slotmap + b * NVOX);
        unsigned int* d32 = (unsigned int*)smap;
        for (int v = threadIdx.x; v < NVOX / 4; v += 256) d32[v] = s32[v];
    }
    __syncthreads();
    int start = ch * CHUNK_L, end = start + CHUNK_L;
    if (useVox) {
        const unsigned short* vb = vox + (size_t)b * NPTS;
        for (int i = start + threadIdx.x * 8; i < end; i += 256 * 8) {
            uint4 w = *(const uint4*)(vb + i);
            unsigned int ids[8] = {w.x & 0xFFFFu, w.x >> 16, w.y & 0xFFFFu, w.y >> 16,
                                   w.z & 0xFFFFu, w.z >> 16, w.w & 0xFFFFu, w.w >> 16};
#pragma unroll
            for (int k = 0; k < 8; ++k) {
                if (ids[k] < NVOX) {
                    unsigned char s = smap[ids[k]];
                    if (s != 0xFF) {
                        unsigned int t = atomicAdd(&tickets[b * VN + s], 1u);
                        if (t < CAP) lists[(size_t)(b * VN + s) * CAP + t] =
                                         (unsigned int)(i + k);
                    }
                }
            }
        }
    } else {
        const float* pb = pc + (size_t)b * NPTS * 3;
        for (int i = start + threadIdx.x; i < end; i += 256) {
            int id = voxid(pb[i * 3], pb[i * 3 + 1], pb[i * 3 + 2]);
            if (id < NVOX) {
                unsigned char s = smap[id];
                if (s != 0xFF) {
                    unsigned int t = atomicAdd(&tickets[b * VN + s], 1u);
                    if (t < CAP) lists[(size_t)(b * VN + s) * CAP + t] = (unsigned int)i;
                }
            }
        }
    }
}

// Pass 3: one wave per (batch, slot) — 40 smallest indices, cyclic gather.
__global__ __launch_bounds__(64) void k_select_gather(const float* __restrict__ pc,
        const int* __restrict__ topvox, const int* __restrict__ topcnt,
        const unsigned int* __restrict__ lists, float* __restrict__ out) {
    __shared__ unsigned int sorted[PMAX];
    int bs = blockIdx.x;
    int b = bs / VN;
    int lane = threadIdx.x;
    int cnt = topcnt[bs];
    float* po = out + OUT_PTS + (size_t)bs * PMAX * 3;
    if (cnt == 0) {
        for (int t = lane; t < PMAX * 3; t += 64) po[t] = 0.0f;
        return;
    }
    int K = cnt < PMAX ? cnt : PMAX;
    if (cnt <= CAP) {
        const unsigned int* L = lists + (size_t)bs * CAP;
        unsigned int vals[CAP / 64];
#pragma unroll
        for (int q = 0; q < CAP / 64; ++q) {
            int e = lane + q * 64;
            vals[q] = (e < cnt) ? L[e] : 0xFFFFFFFFu;
        }
        unsigned int lastp = 0u;
        for (int r = 0; r < K; ++r) {
            unsigned int m = 0xFFFFFFFFu;
#pragma unroll
            for (int q = 0; q < CAP / 64; ++q) {
                unsigned int v = vals[q];
                if (v >= lastp && v < m) m = v;
            }
#pragma unroll
            for (int o = 32; o > 0; o >>= 1) {
                unsigned int t = __shfl_xor(m, o, 64);
                m = (t < m) ? t : m;
            }
            if (lane == 0) sorted[r] = m;
            lastp = m + 1u;
        }
    } else {
        const float* pb = pc + (size_t)b * NPTS * 3;
        int v = topvox[bs];
        int k = 0;
        for (int base = 0; base < NPTS && k < PMAX; base += 64) {
            int i = base + lane;
            int id = voxid(pb[i * 3], pb[i * 3 + 1], pb[i * 3 + 2]);
            unsigned long long mask = __ballot(id == v);
            if (id == v) {
                int rk = k + (int)__popcll(mask & ((1ull << lane) - 1ull));
                if (rk < PMAX) sorted[rk] = (unsigned int)i;
            }
            k += (int)__popcll(mask);
        }
    }
    __syncthreads();
    for (int t = lane; t < PMAX * 3; t += 64) {
        int j = t / 3, kk = t % 3;
        int jj = (cnt >= PMAX) ? j : (j % cnt);
        unsigned int idx = sorted[jj];
        po[t] = pc[((size_t)b * NPTS + idx) * 3 + kk];
    }
}

// Keypoint conditioning, one block per batch. Exact f32, no FMA,
// strict-< argmin, sequential 17-step update done by one thread in LDS.
__global__ __launch_bounds__(64) void k_kc(const float* __restrict__ kpts,
                                           float* __restrict__ out) {
    __shared__ float vl_s[VN * 3];
    __shared__ float kc_s[VN * 6];
    __shared__ float md_s[17];
    __shared__ int mi_s[17];
    int b = blockIdx.x;
    int tid = threadIdx.x;
    const float* vl = out + OUT_VL + b * VN * 3;
    for (int i = tid; i < VN * 3; i += 64) vl_s[i] = vl[i];
    for (int i = tid; i < VN * 6; i += 64) kc_s[i] = 0.0f;
    __syncthreads();
    if (tid < 17) {
        const float* kp = kpts + b * 17 * 3 + tid * 3;
        float a0 = kp[2], a1 = kp[0], a2 = kp[1];  // kq = kpts[:, [2,0,1]]
        float best = 1e30f;
        int bi = 0;
        for (int i = 0; i < VN; ++i) {
            float d0 = __fsub_rn(a0, vl_s[i * 3 + 0]);
            float d1 = __fsub_rn(a1, vl_s[i * 3 + 1]);
            float d2 = __fsub_rn(a2, vl_s[i * 3 + 2]);
            float sq = __fadd_rn(__fadd_rn(__fmul_rn(d0, d0), __fmul_rn(d1, d1)),
                                 __fmul_rn(d2, d2));
            float d = __fsqrt_rn(sq);
            if (d < best) { best = d; bi = i; }
        }
        md_s[tid] = best;
        mi_s[tid] = bi;
    }
    __syncthreads();
    if (tid == 0) {
        for (int j = 0; j < 17; ++j) {
            float e[6] = {KENC[j][0], KENC[j][1], KENC[j][2], KENC[j][3], KENC[j][4],
                          md_s[j]};
            float* row = kc_s + mi_s[j] * 6;
            bool z = true;
            for (int q = 0; q < 6; ++q) z = z && (row[q] == 0.0f);
            for (int q = 0; q < 6; ++q)
                row[q] = z ? e[q] : __fmul_rn(__fadd_rn(row[q], e[q]), 0.5f);
        }
    }
    __syncthreads();
    float* kc = out + OUT_KC + b * VN * 6;
    for (int i = tid; i < VN * 6; i += 64) kc[i] = kc_s[i];
}

extern "C" void kernel_launch(void* const* d_in, const int* in_sizes, int n_in,
                              void* d_out, int out_size, void* d_ws, size_t ws_size,
                              hipStream_t stream) {
    const float* pc = (const float*)d_in[0];
    const float* kpts = (const float*)d_in[1];
    float* out = (float*)d_out;
    char* ws = (char*)d_ws;

    unsigned int* counts = (unsigned int*)(ws + OFF_COUNTS);
    unsigned int* tickets = (unsigned int*)(ws + OFF_TICKETS);
    int* topvox = (int*)(ws + OFF_TOPVOX);
    int* topcnt = (int*)(ws + OFF_TOPCNT);
    unsigned char* slotmap = (unsigned char*)(ws + OFF_SLOTMAP);
    unsigned int* lists = (unsigned int*)(ws + OFF_LISTS);
    unsigned short* vox = (unsigned short*)(ws + OFF_VOX);
    unsigned int* partials = (unsigned int*)(ws + OFF_PART);
    int useVox = (ws_size >= (size_t)OFF_PART) ? 1 : 0;
    int usePart = (ws_size >= (size_t)(OFF_PART + SZ_PART)) ? 1 : 0;

    hipMemsetAsync(ws + OFF_COUNTS, 0, SZ_COUNTS + SZ_TICKETS, stream);
    hipLaunchKernelGGL(k_vox_hist, dim3(BN * NCH_H), dim3(256), 0, stream,
                       pc, counts, vox, partials, useVox, usePart);
    if (usePart)
        hipLaunchKernelGGL(k_reduce_counts, dim3((BN * NVOX + 255) / 256), dim3(256),
                           0, stream, partials, counts);
    hipLaunchKernelGGL(k_topk, dim3(BN), dim3(256), 0, stream,
                       counts, topvox, topcnt, slotmap, out);
    hipLaunchKernelGGL(k_build_lists, dim3(BN * NCH_L), dim3(256), 0, stream,
                       pc, vox, useVox, slotmap, tickets, lists);
    hipLaunchKernelGGL(k_select_gather, dim3(BN * VN), dim3(64), 0, stream,
                       pc, topvox, topcnt, lists, out);
    hipLaunchKernelGGL(k_kc, dim3(BN), dim3(64), 0, stream, kpts, out);
}

// Round 3
// 164.571 us; speedup vs baseline: 2.1940x; 1.0353x over previous
//
#include <hip/hip_runtime.h>
#include <hip/hip_bf16.h>

#define BN 32
#define NPTS 400000
#define NVOX 2560
#define GDYZ 160
#define GDZ 10
#define VN 60
#define PMAX 40
#define CAP 512

/* hist pass geometry */
#define NCH_H 40
#define CHUNK_H (NPTS / NCH_H)   /* 10000, %4 == 0 */
/* list pass geometry */
#define NCH_L 50
#define CHUNK_L (NPTS / NCH_L)   /* 8000, %8 == 0 */

/* ws layout (bytes) */
#define OFF_COUNTS 0
#define SZ_COUNTS (BN * NVOX * 4)                 /* 327680 */
#define OFF_TICKETS (OFF_COUNTS + SZ_COUNTS)
#define SZ_TICKETS (BN * VN * 4)                  /* 7680 */
#define OFF_TOPVOX (OFF_TICKETS + SZ_TICKETS)
#define OFF_TOPCNT (OFF_TOPVOX + BN * VN * 4)
#define OFF_SLOTMAP (OFF_TOPCNT + BN * VN * 4)
#define OFF_LISTS (OFF_SLOTMAP + BN * NVOX)
#define SZ_LISTS (BN * VN * CAP * 4)              /* 3932160 */
#define OFF_VOX (OFF_LISTS + SZ_LISTS)
#define SZ_VOX (BN * NPTS * 2)                    /* 25.6 MB */
#define OFF_PART (OFF_VOX + SZ_VOX)
#define SZ_PART (BN * NCH_H * NVOX * 4)           /* 13.1 MB */

/* out layout (floats) */
#define OUT_PTS 0
#define OUT_VL (BN * VN * PMAX * 3)   /* 230400 */
#define OUT_KC (OUT_VL + BN * VN * 3) /* 236160 */

__device__ __constant__ float KENC[17][5] = {
    {0,0,0,0,1},{0,0,0,1,0},{0,0,0,1,1},{0,0,1,0,0},{0,0,1,0,1},{0,0,1,1,0},
    {0,0,1,1,1},{0,1,0,0,0},{0,1,0,0,1},{0,1,0,1,0},{0,1,0,1,1},{0,1,1,0,0},
    {0,1,1,0,1},{0,1,1,1,0},{0,1,1,1,1},{1,0,0,0,0},{1,0,0,0,1}};

// Exact replica of reference voxelization (IEEE f32 sub + div, trunc).
__device__ __forceinline__ int voxid(float x, float y, float z) {
    float ex = x;
    float ey = __fadd_rn(y, 3.2f);
    float ez = __fadd_rn(z, 2.0f);
    int vx = (int)(ex / 0.4f);
    int vy = (int)(ey / 0.4f);
    int vz = (int)(ez / 0.4f);
    bool valid = !(x == 0.0f && y == 0.0f && z == 0.0f);
    bool inr = (vx >= 0) & (vx < 16) & (vy >= 0) & (vy < 16) & (vz >= 0) & (vz < 10);
    return (valid && inr) ? (vx * GDYZ + vy * GDZ + vz) : 0xFFFF;
}

// Pass 1: voxel-id cache (u16) + per-(batch,chunk) partial histogram.
// No global zeroing needed: partials are fully overwritten each call.
__global__ __launch_bounds__(256) void k_vox_hist(const float* __restrict__ pc,
        unsigned int* __restrict__ counts, unsigned short* __restrict__ vox,
        unsigned int* __restrict__ partials, int useVox, int usePart) {
    __shared__ unsigned int hist[NVOX];
    int b = blockIdx.x / NCH_H;
    int ch = blockIdx.x % NCH_H;
    for (int v = threadIdx.x; v < NVOX; v += 256) hist[v] = 0u;
    __syncthreads();
    const float4* p4 = (const float4*)(pc + (size_t)b * NPTS * 3);
    int start = ch * CHUNK_H, end = start + CHUNK_H;
    for (int g = start + threadIdx.x * 4; g < end; g += 256 * 4) {
        int f = (g * 3) >> 2;  // g % 4 == 0 -> exact
        float4 q0 = p4[f], q1 = p4[f + 1], q2 = p4[f + 2];
        float xs[4] = {q0.x, q0.w, q1.z, q2.y};
        float ys[4] = {q0.y, q1.x, q1.w, q2.z};
        float zs[4] = {q0.z, q1.y, q2.x, q2.w};
        unsigned short ids[4];
#pragma unroll
        for (int k = 0; k < 4; ++k) {
            int id = voxid(xs[k], ys[k], zs[k]);
            ids[k] = (unsigned short)id;
            if (id < NVOX) atomicAdd(&hist[id], 1u);
        }
        if (useVox) *(ushort2*)(&vox[(size_t)b * NPTS + g]) =
                        make_ushort2(ids[0], ids[1]),
                    *(ushort2*)(&vox[(size_t)b * NPTS + g + 2]) = make_ushort2(ids[2], ids[3]);
    }
    __syncthreads();
    if (usePart) {
        unsigned int* dst = partials + ((size_t)b * NCH_H + ch) * NVOX;
        for (int v = threadIdx.x; v < NVOX; v += 256) dst[v] = hist[v];
    } else {
        for (int v = threadIdx.x; v < NVOX; v += 256) {
            unsigned int c = hist[v];
            if (c) atomicAdd(&counts[b * NVOX + v], c);
        }
    }
}

// Pass 1b: counts[b][v] = sum over chunks of partials (fully overwrites counts).
__global__ __launch_bounds__(256) void k_reduce_counts(
        const unsigned int* __restrict__ partials, unsigned int* __restrict__ counts) {
    int t = blockIdx.x * 256 + threadIdx.x;
    if (t >= BN * NVOX) return;
    int b = t / NVOX, v = t % NVOX;
    const unsigned int* src = partials + (size_t)b * NCH_H * NVOX + v;
    unsigned int s = 0;
#pragma unroll 8
    for (int c = 0; c < NCH_H; ++c) s += src[(size_t)c * NVOX];
    counts[t] = s;
}

// Per-batch top-60 by (count desc, index asc) == jax.lax.top_k order.
// Also zeroes this batch's tickets (runs before k_build_lists).
__global__ __launch_bounds__(256) void k_topk(const unsigned int* __restrict__ counts,
        int* __restrict__ topvox, int* __restrict__ topcnt,
        unsigned char* __restrict__ slotmap, unsigned int* __restrict__ tickets,
        float* __restrict__ out) {
    __shared__ unsigned int keys[NVOX];
    __shared__ unsigned int red[4];
    int b = blockIdx.x;
    int tid = threadIdx.x;
    for (int v = tid; v < NVOX; v += 256) {
        keys[v] = (counts[b * NVOX + v] << 12) | (unsigned int)(4095 - v);
        slotmap[b * NVOX + v] = 0xFF;
    }
    if (tid < VN) tickets[b * VN + tid] = 0u;
    __syncthreads();
    for (int r = 0; r < VN; ++r) {
        unsigned int m = 0u;
        for (int v = tid; v < NVOX; v += 256) {
            unsigned int k = keys[v];
            m = (k > m) ? k : m;
        }
#pragma unroll
        for (int o = 32; o > 0; o >>= 1) {
            unsigned int t = __shfl_xor(m, o, 64);
            m = (t > m) ? t : m;
        }
        if ((tid & 63) == 0) red[tid >> 6] = m;
        __syncthreads();
        if (tid == 0) {
            unsigned int best = red[0];
            if (red[1] > best) best = red[1];
            if (red[2] > best) best = red[2];
            if (red[3] > best) best = red[3];
            int v = 4095 - (int)(best & 4095u);
            topvox[b * VN + r] = v;
            topcnt[b * VN + r] = (int)(best >> 12);
            slotmap[b * NVOX + v] = (unsigned char)r;
            keys[v] = 0u;
        }
        __syncthreads();
    }
    if (tid < VN) {
        int v = topvox[b * VN + tid];
        int vx = v / GDYZ, rem = v % GDYZ, vy = rem / GDZ, vz = rem % GDZ;
        float c0 = __fadd_rn(__fmul_rn((float)vx, 0.4f), 0.2f);
        float c1 = __fadd_rn(__fadd_rn(-3.2f, __fmul_rn((float)vy, 0.4f)), 0.2f);
        float c2 = __fadd_rn(__fadd_rn(-2.0f, __fmul_rn((float)vz, 0.4f)), 0.2f);
        float* vl = out + OUT_VL + (b * VN + tid) * 3;
        vl[0] = c0; vl[1] = c1; vl[2] = c2;
    }
}

// Pass 2: for each point in a selected voxel, grab a ticket and record index.
__global__ __launch_bounds__(256) void k_build_lists(const float* __restrict__ pc,
        const unsigned short* __restrict__ vox, int useVox,
        const unsigned char* __restrict__ slotmap,
        unsigned int* __restrict__ tickets, unsigned int* __restrict__ lists) {
    __shared__ unsigned char smap[NVOX];
    int b = blockIdx.x / NCH_L;
    int ch = blockIdx.x % NCH_L;
    {
        const unsigned int* s32 = (const unsigned int*)(slotmap + b * NVOX);
        unsigned int* d32 = (unsigned int*)smap;
        for (int v = threadIdx.x; v < NVOX / 4; v += 256) d32[v] = s32[v];
    }
    __syncthreads();
    int start = ch * CHUNK_L, end = start + CHUNK_L;
    if (useVox) {
        const unsigned short* vb = vox + (size_t)b * NPTS;
        for (int i = start + threadIdx.x * 8; i < end; i += 256 * 8) {
            uint4 w = *(const uint4*)(vb + i);
            unsigned int ids[8] = {w.x & 0xFFFFu, w.x >> 16, w.y & 0xFFFFu, w.y >> 16,
                                   w.z & 0xFFFFu, w.z >> 16, w.w & 0xFFFFu, w.w >> 16};
#pragma unroll
            for (int k = 0; k < 8; ++k) {
                if (ids[k] < NVOX) {
                    unsigned char s = smap[ids[k]];
                    if (s != 0xFF) {
                        unsigned int t = atomicAdd(&tickets[b * VN + s], 1u);
                        if (t < CAP) lists[(size_t)(b * VN + s) * CAP + t] =
                                         (unsigned int)(i + k);
                    }
                }
            }
        }
    } else {
        const float* pb = pc + (size_t)b * NPTS * 3;
        for (int i = start + threadIdx.x; i < end; i += 256) {
            int id = voxid(pb[i * 3], pb[i * 3 + 1], pb[i * 3 + 2]);
            if (id < NVOX) {
                unsigned char s = smap[id];
                if (s != 0xFF) {
                    unsigned int t = atomicAdd(&tickets[b * VN + s], 1u);
                    if (t < CAP) lists[(size_t)(b * VN + s) * CAP + t] = (unsigned int)i;
                }
            }
        }
    }
}

// Pass 3: one wave per (batch, slot) — 40 smallest indices, cyclic gather.
__global__ __launch_bounds__(64) void k_select_gather(const float* __restrict__ pc,
        const int* __restrict__ topvox, const int* __restrict__ topcnt,
        const unsigned int* __restrict__ lists, float* __restrict__ out) {
    __shared__ unsigned int sorted[PMAX];
    int bs = blockIdx.x;
    int b = bs / VN;
    int lane = threadIdx.x;
    int cnt = topcnt[bs];
    float* po = out + OUT_PTS + (size_t)bs * PMAX * 3;
    if (cnt == 0) {
        for (int t = lane; t < PMAX * 3; t += 64) po[t] = 0.0f;
        return;
    }
    int K = cnt < PMAX ? cnt : PMAX;
    if (cnt <= CAP) {
        const unsigned int* L = lists + (size_t)bs * CAP;
        unsigned int vals[CAP / 64];
#pragma unroll
        for (int q = 0; q < CAP / 64; ++q) {
            int e = lane + q * 64;
            vals[q] = (e < cnt) ? L[e] : 0xFFFFFFFFu;
        }
        unsigned int lastp = 0u;
        for (int r = 0; r < K; ++r) {
            unsigned int m = 0xFFFFFFFFu;
#pragma unroll
            for (int q = 0; q < CAP / 64; ++q) {
                unsigned int v = vals[q];
                if (v >= lastp && v < m) m = v;
            }
#pragma unroll
            for (int o = 32; o > 0; o >>= 1) {
                unsigned int t = __shfl_xor(m, o, 64);
                m = (t < m) ? t : m;
            }
            if (lane == 0) sorted[r] = m;
            lastp = m + 1u;
        }
    } else {
        const float* pb = pc + (size_t)b * NPTS * 3;
        int v = topvox[bs];
        int k = 0;
        for (int base = 0; base < NPTS && k < PMAX; base += 64) {
            int i = base + lane;
            int id = voxid(pb[i * 3], pb[i * 3 + 1], pb[i * 3 + 2]);
            unsigned long long mask = __ballot(id == v);
            if (id == v) {
                int rk = k + (int)__popcll(mask & ((1ull << lane) - 1ull));
                if (rk < PMAX) sorted[rk] = (unsigned int)i;
            }
            k += (int)__popcll(mask);
        }
    }
    __syncthreads();
    for (int t = lane; t < PMAX * 3; t += 64) {
        int j = t / 3, kk = t % 3;
        int jj = (cnt >= PMAX) ? j : (j % cnt);
        unsigned int idx = sorted[jj];
        po[t] = pc[((size_t)b * NPTS + idx) * 3 + kk];
    }
}

// Keypoint conditioning, one block per batch. Exact f32, no FMA,
// strict-< argmin, sequential 17-step update done by one thread in LDS.
__global__ __launch_bounds__(64) void k_kc(const float* __restrict__ kpts,
                                           float* __restrict__ out) {
    __shared__ float vl_s[VN * 3];
    __shared__ float kc_s[VN * 6];
    __shared__ float md_s[17];
    __shared__ int mi_s[17];
    int b = blockIdx.x;
    int tid = threadIdx.x;
    const float* vl = out + OUT_VL + b * VN * 3;
    for (int i = tid; i < VN * 3; i += 64) vl_s[i] = vl[i];
    for (int i = tid; i < VN * 6; i += 64) kc_s[i] = 0.0f;
    __syncthreads();
    if (tid < 17) {
        const float* kp = kpts + b * 17 * 3 + tid * 3;
        float a0 = kp[2], a1 = kp[0], a2 = kp[1];  // kq = kpts[:, [2,0,1]]
        float best = 1e30f;
        int bi = 0;
        for (int i = 0; i < VN; ++i) {
            float d0 = __fsub_rn(a0, vl_s[i * 3 + 0]);
            float d1 = __fsub_rn(a1, vl_s[i * 3 + 1]);
            float d2 = __fsub_rn(a2, vl_s[i * 3 + 2]);
            float sq = __fadd_rn(__fadd_rn(__fmul_rn(d0, d0), __fmul_rn(d1, d1)),
                                 __fmul_rn(d2, d2));
            float d = __fsqrt_rn(sq);
            if (d < best) { best = d; bi = i; }
        }
        md_s[tid] = best;
        mi_s[tid] = bi;
    }
    __syncthreads();
    if (tid == 0) {
        for (int j = 0; j < 17; ++j) {
            float e[6] = {KENC[j][0], KENC[j][1], KENC[j][2], KENC[j][3], KENC[j][4],
                          md_s[j]};
            float* row = kc_s + mi_s[j] * 6;
            bool z = true;
            for (int q = 0; q < 6; ++q) z = z && (row[q] == 0.0f);
            for (int q = 0; q < 6; ++q)
                row[q] = z ? e[q] : __fmul_rn(__fadd_rn(row[q], e[q]), 0.5f);
        }
    }
    __syncthreads();
    float* kc = out + OUT_KC + b * VN * 6;
    for (int i = tid; i < VN * 6; i += 64) kc[i] = kc_s[i];
}

extern "C" void kernel_launch(void* const* d_in, const int* in_sizes, int n_in,
                              void* d_out, int out_size, void* d_ws, size_t ws_size,
                              hipStream_t stream) {
    const float* pc = (const float*)d_in[0];
    const float* kpts = (const float*)d_in[1];
    float* out = (float*)d_out;
    char* ws = (char*)d_ws;

    unsigned int* counts = (unsigned int*)(ws + OFF_COUNTS);
    unsigned int* tickets = (unsigned int*)(ws + OFF_TICKETS);
    int* topvox = (int*)(ws + OFF_TOPVOX);
    int* topcnt = (int*)(ws + OFF_TOPCNT);
    unsigned char* slotmap = (unsigned char*)(ws + OFF_SLOTMAP);
    unsigned int* lists = (unsigned int*)(ws + OFF_LISTS);
    unsigned short* vox = (unsigned short*)(ws + OFF_VOX);
    unsigned int* partials = (unsigned int*)(ws + OFF_PART);
    int useVox = (ws_size >= (size_t)OFF_PART) ? 1 : 0;
    int usePart = (ws_size >= (size_t)(OFF_PART + SZ_PART)) ? 1 : 0;

    // Primary path needs NO memset: counts is fully overwritten by
    // k_reduce_counts, tickets are zeroed inside k_topk. Only the tiny-ws
    // fallback (never taken with this harness) needs counts pre-zeroed.
    if (!usePart)
        hipMemsetAsync(ws + OFF_COUNTS, 0, SZ_COUNTS, stream);

    hipLaunchKernelGGL(k_vox_hist, dim3(BN * NCH_H), dim3(256), 0, stream,
                       pc, counts, vox, partials, useVox, usePart);
    if (usePart)
        hipLaunchKernelGGL(k_reduce_counts, dim3((BN * NVOX + 255) / 256), dim3(256),
                           0, stream, partials, counts);
    hipLaunchKernelGGL(k_topk, dim3(BN), dim3(256), 0, stream,
                       counts, topvox, topcnt, slotmap, tickets, out);
    hipLaunchKernelGGL(k_build_lists, dim3(BN * NCH_L), dim3(256), 0, stream,
                       pc, vox, useVox, slotmap, tickets, lists);
    hipLaunchKernelGGL(k_select_gather, dim3(BN * VN), dim3(64), 0, stream,
                       pc, topvox, topcnt, lists, out);
    hipLaunchKernelGGL(k_kc, dim3(BN), dim3(64), 0, stream, kpts, out);
}

// Round 4
// 148.626 us; speedup vs baseline: 2.4294x; 1.1073x over previous
//
#include <hip/hip_runtime.h>
#include <hip/hip_bf16.h>

#define BN 32
#define NPTS 400000
#define NVOX 2560
#define GDYZ 160
#define GDZ 10
#define VN 60
#define PMAX 40
#define CAP 512

/* hist pass geometry */
#define NCH_H 40
#define CHUNK_H (NPTS / NCH_H)   /* 10000, %4 == 0 */
/* list pass geometry */
#define NCH_L 50
#define CHUNK_L (NPTS / NCH_L)   /* 8000, %8 == 0 */

/* ws layout (bytes) */
#define OFF_COUNTS 0
#define SZ_COUNTS (BN * NVOX * 4)                 /* 327680 */
#define OFF_TICKETS (OFF_COUNTS + SZ_COUNTS)
#define SZ_TICKETS (BN * VN * 4)                  /* 7680 */
#define OFF_TOPVOX (OFF_TICKETS + SZ_TICKETS)
#define OFF_TOPCNT (OFF_TOPVOX + BN * VN * 4)
#define OFF_SLOTMAP (OFF_TOPCNT + BN * VN * 4)
#define OFF_LISTS (OFF_SLOTMAP + BN * NVOX)
#define SZ_LISTS (BN * VN * CAP * 4)              /* 3932160 */
#define OFF_VOX (OFF_LISTS + SZ_LISTS)
#define SZ_VOX (BN * NPTS * 2)                    /* 25.6 MB */
#define OFF_PART (OFF_VOX + SZ_VOX)
#define SZ_PART (BN * NCH_H * NVOX * 4)           /* 13.1 MB */

/* out layout (floats) */
#define OUT_PTS 0
#define OUT_VL (BN * VN * PMAX * 3)   /* 230400 */
#define OUT_KC (OUT_VL + BN * VN * 3) /* 236160 */

__device__ __constant__ float KENC[17][5] = {
    {0,0,0,0,1},{0,0,0,1,0},{0,0,0,1,1},{0,0,1,0,0},{0,0,1,0,1},{0,0,1,1,0},
    {0,0,1,1,1},{0,1,0,0,0},{0,1,0,0,1},{0,1,0,1,0},{0,1,0,1,1},{0,1,1,0,0},
    {0,1,1,0,1},{0,1,1,1,0},{0,1,1,1,1},{1,0,0,0,0},{1,0,0,0,1}};

// Exact replica of reference voxelization (IEEE f32 sub + div, trunc).
__device__ __forceinline__ int voxid(float x, float y, float z) {
    float ex = x;
    float ey = __fadd_rn(y, 3.2f);
    float ez = __fadd_rn(z, 2.0f);
    int vx = (int)(ex / 0.4f);
    int vy = (int)(ey / 0.4f);
    int vz = (int)(ez / 0.4f);
    bool valid = !(x == 0.0f && y == 0.0f && z == 0.0f);
    bool inr = (vx >= 0) & (vx < 16) & (vy >= 0) & (vy < 16) & (vz >= 0) & (vz < 10);
    return (valid && inr) ? (vx * GDYZ + vy * GDZ + vz) : 0xFFFF;
}

// Pass 1: voxel-id cache (u16) + per-(batch,chunk) partial histogram.
__global__ __launch_bounds__(256) void k_vox_hist(const float* __restrict__ pc,
        unsigned int* __restrict__ counts, unsigned short* __restrict__ vox,
        unsigned int* __restrict__ partials, int useVox, int usePart) {
    __shared__ unsigned int hist[NVOX];
    int b = blockIdx.x / NCH_H;
    int ch = blockIdx.x % NCH_H;
    for (int v = threadIdx.x; v < NVOX; v += 256) hist[v] = 0u;
    __syncthreads();
    const float4* p4 = (const float4*)(pc + (size_t)b * NPTS * 3);
    int start = ch * CHUNK_H, end = start + CHUNK_H;
    for (int g = start + threadIdx.x * 4; g < end; g += 256 * 4) {
        int f = (g * 3) >> 2;  // g % 4 == 0 -> exact
        float4 q0 = p4[f], q1 = p4[f + 1], q2 = p4[f + 2];
        float xs[4] = {q0.x, q0.w, q1.z, q2.y};
        float ys[4] = {q0.y, q1.x, q1.w, q2.z};
        float zs[4] = {q0.z, q1.y, q2.x, q2.w};
        unsigned short ids[4];
#pragma unroll
        for (int k = 0; k < 4; ++k) {
            int id = voxid(xs[k], ys[k], zs[k]);
            ids[k] = (unsigned short)id;
            if (id < NVOX) atomicAdd(&hist[id], 1u);
        }
        if (useVox)
            *(ushort4*)(&vox[(size_t)b * NPTS + g]) =
                make_ushort4(ids[0], ids[1], ids[2], ids[3]);
    }
    __syncthreads();
    if (usePart) {
        unsigned int* dst = partials + ((size_t)b * NCH_H + ch) * NVOX;
        for (int v = threadIdx.x; v < NVOX; v += 256) dst[v] = hist[v];
    } else {
        for (int v = threadIdx.x; v < NVOX; v += 256) {
            unsigned int c = hist[v];
            if (c) atomicAdd(&counts[b * NVOX + v], c);
        }
    }
}

// Pass 1b: counts = sum over chunks of partials (uint4-vectorized).
__global__ __launch_bounds__(256) void k_reduce_counts(
        const uint4* __restrict__ partials4, uint4* __restrict__ counts4) {
    int t = blockIdx.x * 256 + threadIdx.x;   // indexes uint4 (4 voxels)
    if (t >= BN * NVOX / 4) return;
    int b = t / (NVOX / 4), q = t % (NVOX / 4);
    const uint4* src = partials4 + (size_t)b * NCH_H * (NVOX / 4) + q;
    uint4 s = make_uint4(0u, 0u, 0u, 0u);
#pragma unroll 8
    for (int c = 0; c < NCH_H; ++c) {
        uint4 w = src[(size_t)c * (NVOX / 4)];
        s.x += w.x; s.y += w.y; s.z += w.z; s.w += w.w;
    }
    counts4[t] = s;
}

// Per-batch top-60 by (count desc, index asc) == jax.lax.top_k order.
// Single wave; keys are lane-private (slot v == lane mod 64), so the
// 60-round selection needs no barriers: per-thread register max +
// owner-only rescan after each extraction. Also zeroes tickets.
__global__ __launch_bounds__(64) void k_topk(const unsigned int* __restrict__ counts,
        int* __restrict__ topvox, int* __restrict__ topcnt,
        unsigned char* __restrict__ slotmap, unsigned int* __restrict__ tickets,
        float* __restrict__ out) {
    __shared__ unsigned int keys[NVOX];
    __shared__ int svox[VN];
    int b = blockIdx.x;
    int tid = threadIdx.x;
    unsigned int mloc = 0u;
    for (int v = tid; v < NVOX; v += 64) {
        unsigned int k = (counts[b * NVOX + v] << 12) | (unsigned int)(4095 - v);
        keys[v] = k;
        if (k > mloc) mloc = k;
    }
    {   // slotmap = 0xFF via u32 stores
        unsigned int* d32 = (unsigned int*)(slotmap + b * NVOX);
        for (int w = tid; w < NVOX / 4; w += 64) d32[w] = 0xFFFFFFFFu;
    }
    if (tid < VN) tickets[b * VN + tid] = 0u;
    __syncthreads();
    for (int r = 0; r < VN; ++r) {
        unsigned int m = mloc;
#pragma unroll
        for (int o = 32; o > 0; o >>= 1) {
            unsigned int t2 = __shfl_xor(m, o, 64);
            if (t2 > m) m = t2;
        }
        // exactly one lane owns the max (keys unique)
        if (mloc == m) {
            int v = 4095 - (int)(m & 4095u);
            topvox[b * VN + r] = v;
            topcnt[b * VN + r] = (int)(m >> 12);
            slotmap[b * NVOX + v] = (unsigned char)r;
            svox[r] = v;
            keys[v] = 0u;                      // lane-private slot
            mloc = 0u;
            for (int vv = tid; vv < NVOX; vv += 64) {
                unsigned int k = keys[vv];
                if (k > mloc) mloc = k;
            }
        }
    }
    __syncthreads();
    if (tid < VN) {
        int v = svox[tid];
        int vx = v / GDYZ, rem = v % GDYZ, vy = rem / GDZ, vz = rem % GDZ;
        float c0 = __fadd_rn(__fmul_rn((float)vx, 0.4f), 0.2f);
        float c1 = __fadd_rn(__fadd_rn(-3.2f, __fmul_rn((float)vy, 0.4f)), 0.2f);
        float c2 = __fadd_rn(__fadd_rn(-2.0f, __fmul_rn((float)vz, 0.4f)), 0.2f);
        float* vl = out + OUT_VL + (b * VN + tid) * 3;
        vl[0] = c0; vl[1] = c1; vl[2] = c2;
    }
}

// Pass 2: for each point in a selected voxel, grab a ticket and record index.
__global__ __launch_bounds__(256) void k_build_lists(const float* __restrict__ pc,
        const unsigned short* __restrict__ vox, int useVox,
        const unsigned char* __restrict__ slotmap,
        unsigned int* __restrict__ tickets, unsigned int* __restrict__ lists) {
    __shared__ unsigned char smap[NVOX];
    int b = blockIdx.x / NCH_L;
    int ch = blockIdx.x % NCH_L;
    {
        const unsigned int* s32 = (const unsigned int*)(slotmap + b * NVOX);
        unsigned int* d32 = (unsigned int*)smap;
        for (int v = threadIdx.x; v < NVOX / 4; v += 256) d32[v] = s32[v];
    }
    __syncthreads();
    int start = ch * CHUNK_L, end = start + CHUNK_L;
    if (useVox) {
        const unsigned short* vb = vox + (size_t)b * NPTS;
        for (int i = start + threadIdx.x * 8; i < end; i += 256 * 8) {
            uint4 w = *(const uint4*)(vb + i);
            unsigned int ids[8] = {w.x & 0xFFFFu, w.x >> 16, w.y & 0xFFFFu, w.y >> 16,
                                   w.z & 0xFFFFu, w.z >> 16, w.w & 0xFFFFu, w.w >> 16};
#pragma unroll
            for (int k = 0; k < 8; ++k) {
                if (ids[k] < NVOX) {
                    unsigned char s = smap[ids[k]];
                    if (s != 0xFF) {
                        unsigned int t = atomicAdd(&tickets[b * VN + s], 1u);
                        if (t < CAP) lists[(size_t)(b * VN + s) * CAP + t] =
                                         (unsigned int)(i + k);
                    }
                }
            }
        }
    } else {
        const float* pb = pc + (size_t)b * NPTS * 3;
        for (int i = start + threadIdx.x; i < end; i += 256) {
            int id = voxid(pb[i * 3], pb[i * 3 + 1], pb[i * 3 + 2]);
            if (id < NVOX) {
                unsigned char s = smap[id];
                if (s != 0xFF) {
                    unsigned int t = atomicAdd(&tickets[b * VN + s], 1u);
                    if (t < CAP) lists[(size_t)(b * VN + s) * CAP + t] = (unsigned int)i;
                }
            }
        }
    }
}

// Pass 3 (merged): blocks [0, BN*VN) = select+gather; blocks [BN*VN, +BN) = kc.
__global__ __launch_bounds__(64) void k_select_kc(const float* __restrict__ pc,
        const float* __restrict__ kpts,
        const int* __restrict__ topvox, const int* __restrict__ topcnt,
        const unsigned int* __restrict__ lists, float* __restrict__ out) {
    __shared__ unsigned int sorted[PMAX];
    __shared__ float vl_s[VN * 3];
    __shared__ float kc_s[VN * 6];
    __shared__ float md_s[17];
    __shared__ int mi_s[17];
    int bs = blockIdx.x;
    int lane = threadIdx.x;

    if (bs >= BN * VN) {
        // ---- keypoint conditioning for batch b ----
        int b = bs - BN * VN;
        const float* vl = out + OUT_VL + b * VN * 3;
        for (int i = lane; i < VN * 3; i += 64) vl_s[i] = vl[i];
        for (int i = lane; i < VN * 6; i += 64) kc_s[i] = 0.0f;
        __syncthreads();
        if (lane < 17) {
            const float* kp = kpts + b * 17 * 3 + lane * 3;
            float a0 = kp[2], a1 = kp[0], a2 = kp[1];  // kq = kpts[:, [2,0,1]]
            float best = 1e30f;
            int bi = 0;
            for (int i = 0; i < VN; ++i) {
                float d0 = __fsub_rn(a0, vl_s[i * 3 + 0]);
                float d1 = __fsub_rn(a1, vl_s[i * 3 + 1]);
                float d2 = __fsub_rn(a2, vl_s[i * 3 + 2]);
                float sq = __fadd_rn(__fadd_rn(__fmul_rn(d0, d0), __fmul_rn(d1, d1)),
                                     __fmul_rn(d2, d2));
                float d = __fsqrt_rn(sq);
                if (d < best) { best = d; bi = i; }
            }
            md_s[lane] = best;
            mi_s[lane] = bi;
        }
        __syncthreads();
        if (lane == 0) {
            for (int j = 0; j < 17; ++j) {
                float e[6] = {KENC[j][0], KENC[j][1], KENC[j][2], KENC[j][3],
                              KENC[j][4], md_s[j]};
                float* row = kc_s + mi_s[j] * 6;
                bool z = true;
                for (int q = 0; q < 6; ++q) z = z && (row[q] == 0.0f);
                for (int q = 0; q < 6; ++q)
                    row[q] = z ? e[q] : __fmul_rn(__fadd_rn(row[q], e[q]), 0.5f);
            }
        }
        __syncthreads();
        float* kc = out + OUT_KC + b * VN * 6;
        for (int i = lane; i < VN * 6; i += 64) kc[i] = kc_s[i];
        return;
    }

    // ---- select 40 smallest indices + cyclic gather ----
    int b = bs / VN;
    int cnt = topcnt[bs];
    float* po = out + OUT_PTS + (size_t)bs * PMAX * 3;
    if (cnt == 0) {
        for (int t = lane; t < PMAX * 3; t += 64) po[t] = 0.0f;
        return;
    }
    int K = cnt < PMAX ? cnt : PMAX;
    if (cnt <= CAP) {
        const unsigned int* L = lists + (size_t)bs * CAP;
        unsigned int vals[CAP / 64];
#pragma unroll
        for (int q = 0; q < CAP / 64; ++q) {
            int e = lane + q * 64;
            vals[q] = (e < cnt) ? L[e] : 0xFFFFFFFFu;
        }
        unsigned int lastp = 0u;
        for (int r = 0; r < K; ++r) {
            unsigned int m = 0xFFFFFFFFu;
#pragma unroll
            for (int q = 0; q < CAP / 64; ++q) {
                unsigned int v = vals[q];
                if (v >= lastp && v < m) m = v;
            }
#pragma unroll
            for (int o = 32; o > 0; o >>= 1) {
                unsigned int t = __shfl_xor(m, o, 64);
                m = (t < m) ? t : m;
            }
            if (lane == 0) sorted[r] = m;
            lastp = m + 1u;
        }
    } else {
        const float* pb = pc + (size_t)b * NPTS * 3;
        int v = topvox[bs];
        int k = 0;
        for (int base = 0; base < NPTS && k < PMAX; base += 64) {
            int i = base + lane;
            int id = voxid(pb[i * 3], pb[i * 3 + 1], pb[i * 3 + 2]);
            unsigned long long mask = __ballot(id == v);
            if (id == v) {
                int rk = k + (int)__popcll(mask & ((1ull << lane) - 1ull));
                if (rk < PMAX) sorted[rk] = (unsigned int)i;
            }
            k += (int)__popcll(mask);
        }
    }
    __syncthreads();
    for (int t = lane; t < PMAX * 3; t += 64) {
        int j = t / 3, kk = t % 3;
        int jj = (cnt >= PMAX) ? j : (j % cnt);
        unsigned int idx = sorted[jj];
        po[t] = pc[((size_t)b * NPTS + idx) * 3 + kk];
    }
}

extern "C" void kernel_launch(void* const* d_in, const int* in_sizes, int n_in,
                              void* d_out, int out_size, void* d_ws, size_t ws_size,
                              hipStream_t stream) {
    const float* pc = (const float*)d_in[0];
    const float* kpts = (const float*)d_in[1];
    float* out = (float*)d_out;
    char* ws = (char*)d_ws;

    unsigned int* counts = (unsigned int*)(ws + OFF_COUNTS);
    unsigned int* tickets = (unsigned int*)(ws + OFF_TICKETS);
    int* topvox = (int*)(ws + OFF_TOPVOX);
    int* topcnt = (int*)(ws + OFF_TOPCNT);
    unsigned char* slotmap = (unsigned char*)(ws + OFF_SLOTMAP);
    unsigned int* lists = (unsigned int*)(ws + OFF_LISTS);
    unsigned short* vox = (unsigned short*)(ws + OFF_VOX);
    unsigned int* partials = (unsigned int*)(ws + OFF_PART);
    int useVox = (ws_size >= (size_t)OFF_PART) ? 1 : 0;
    int usePart = (ws_size >= (size_t)(OFF_PART + SZ_PART)) ? 1 : 0;

    if (!usePart)  // fallback only; primary path fully overwrites counts
        hipMemsetAsync(ws + OFF_COUNTS, 0, SZ_COUNTS, stream);

    hipLaunchKernelGGL(k_vox_hist, dim3(BN * NCH_H), dim3(256), 0, stream,
                       pc, counts, vox, partials, useVox, usePart);
    if (usePart)
        hipLaunchKernelGGL(k_reduce_counts, dim3((BN * NVOX / 4 + 255) / 256),
                           dim3(256), 0, stream,
                           (const uint4*)partials, (uint4*)counts);
    hipLaunchKernelGGL(k_topk, dim3(BN), dim3(64), 0, stream,
                       counts, topvox, topcnt, slotmap, tickets, out);
    hipLaunchKernelGGL(k_build_lists, dim3(BN * NCH_L), dim3(256), 0, stream,
                       pc, vox, useVox, slotmap, tickets, lists);
    hipLaunchKernelGGL(k_select_kc, dim3(BN * VN + BN), dim3(64), 0, stream,
                       pc, kpts, topvox, topcnt, lists, out);
}

// Round 5
// 130.058 us; speedup vs baseline: 2.7762x; 1.1428x over previous
//
#include <hip/hip_runtime.h>
#include <hip/hip_bf16.h>

#define BN 32
#define NPTS 400000
#define NVOX 2560
#define GDYZ 160
#define GDZ 10
#define VN 60
#define PMAX 40
#define CAP 512

/* hist pass geometry */
#define NCH_H 16
#define CHUNK_H (NPTS / NCH_H)   /* 25000, %4 == 0 */
/* list pass geometry */
#define NCH_L 50
#define CHUNK_L (NPTS / NCH_L)   /* 8000, %8 == 0 */

/* ws layout (bytes) */
#define OFF_COUNTS 0
#define SZ_COUNTS (BN * NVOX * 4)                 /* 327680 */
#define OFF_TICKETS (OFF_COUNTS + SZ_COUNTS)
#define SZ_TICKETS (BN * VN * 4)                  /* 7680 */
#define OFF_TOPVOX (OFF_TICKETS + SZ_TICKETS)
#define OFF_TOPCNT (OFF_TOPVOX + BN * VN * 4)
#define OFF_SLOTMAP (OFF_TOPCNT + BN * VN * 4)
#define OFF_LISTS (OFF_SLOTMAP + BN * NVOX)
#define SZ_LISTS (BN * VN * CAP * 4)              /* 3932160 */
#define OFF_VOX (OFF_LISTS + SZ_LISTS)
#define SZ_VOX (BN * NPTS * 2)                    /* 25.6 MB */
#define OFF_PART (OFF_VOX + SZ_VOX)
#define SZ_PART (BN * NCH_H * NVOX * 4)           /* 5.2 MB */

/* out layout (floats) */
#define OUT_PTS 0
#define OUT_VL (BN * VN * PMAX * 3)   /* 230400 */
#define OUT_KC (OUT_VL + BN * VN * 3) /* 236160 */

__device__ __constant__ float KENC[17][5] = {
    {0,0,0,0,1},{0,0,0,1,0},{0,0,0,1,1},{0,0,1,0,0},{0,0,1,0,1},{0,0,1,1,0},
    {0,0,1,1,1},{0,1,0,0,0},{0,1,0,0,1},{0,1,0,1,0},{0,1,0,1,1},{0,1,1,0,0},
    {0,1,1,0,1},{0,1,1,1,0},{0,1,1,1,1},{1,0,0,0,0},{1,0,0,0,1}};

// Exact replica of reference voxelization (IEEE f32 sub + div, trunc).
__device__ __forceinline__ int voxid(float x, float y, float z) {
    float ex = x;
    float ey = __fadd_rn(y, 3.2f);
    float ez = __fadd_rn(z, 2.0f);
    int vx = (int)(ex / 0.4f);
    int vy = (int)(ey / 0.4f);
    int vz = (int)(ez / 0.4f);
    bool valid = !(x == 0.0f && y == 0.0f && z == 0.0f);
    bool inr = (vx >= 0) & (vx < 16) & (vy >= 0) & (vy < 16) & (vz >= 0) & (vz < 10);
    return (valid && inr) ? (vx * GDYZ + vy * GDZ + vz) : 0xFFFF;
}

// Pass 1: voxel-id cache (u16) + per-(batch,chunk) partial histogram.
__global__ __launch_bounds__(256) void k_vox_hist(const float* __restrict__ pc,
        unsigned int* __restrict__ counts, unsigned short* __restrict__ vox,
        unsigned int* __restrict__ partials, int useVox, int usePart) {
    __shared__ unsigned int hist[NVOX];
    int b = blockIdx.x / NCH_H;
    int ch = blockIdx.x % NCH_H;
    for (int v = threadIdx.x; v < NVOX; v += 256) hist[v] = 0u;
    __syncthreads();
    const float4* p4 = (const float4*)(pc + (size_t)b * NPTS * 3);
    int start = ch * CHUNK_H, end = start + CHUNK_H;
    for (int g = start + threadIdx.x * 4; g < end; g += 256 * 4) {
        int f = (g * 3) >> 2;  // g % 4 == 0 -> exact
        float4 q0 = p4[f], q1 = p4[f + 1], q2 = p4[f + 2];
        float xs[4] = {q0.x, q0.w, q1.z, q2.y};
        float ys[4] = {q0.y, q1.x, q1.w, q2.z};
        float zs[4] = {q0.z, q1.y, q2.x, q2.w};
        unsigned short ids[4];
#pragma unroll
        for (int k = 0; k < 4; ++k) {
            int id = voxid(xs[k], ys[k], zs[k]);
            ids[k] = (unsigned short)id;
            if (id < NVOX) atomicAdd(&hist[id], 1u);
        }
        if (useVox)
            *(ushort4*)(&vox[(size_t)b * NPTS + g]) =
                make_ushort4(ids[0], ids[1], ids[2], ids[3]);
    }
    __syncthreads();
    if (usePart) {
        unsigned int* dst = partials + ((size_t)b * NCH_H + ch) * NVOX;
        for (int v = threadIdx.x; v < NVOX; v += 256) dst[v] = hist[v];
    } else {
        for (int v = threadIdx.x; v < NVOX; v += 256) {
            unsigned int c = hist[v];
            if (c) atomicAdd(&counts[b * NVOX + v], c);
        }
    }
}

// Pass 1b+2 fused: per-batch counts reduce + exact top-60 by
// (count desc, index asc) == jax.lax.top_k order.
// Selection: keys are unique u32; binary-search the 60th-largest key,
// collect the exactly-60 keys >= it, rank by pairwise comparison.
// All selection work happens in wave 0 (no barriers after init).
__global__ __launch_bounds__(256) void k_topk(
        const unsigned int* __restrict__ partials,
        const unsigned int* __restrict__ counts, int usePart,
        int* __restrict__ topvox, int* __restrict__ topcnt,
        unsigned char* __restrict__ slotmap, unsigned int* __restrict__ tickets,
        float* __restrict__ out) {
    __shared__ unsigned int keys[NVOX];
    __shared__ unsigned int cand[VN];
    __shared__ unsigned int ncand;
    int b = blockIdx.x;
    int tid = threadIdx.x;
    if (usePart) {
#pragma unroll
        for (int k = 0; k < NVOX / 256; ++k) {   // 10 voxels/thread
            int v = tid + 256 * k;
            const unsigned int* src = partials + (size_t)b * NCH_H * NVOX + v;
            unsigned int s = 0;
#pragma unroll
            for (int c = 0; c < NCH_H; ++c) s += src[(size_t)c * NVOX];
            keys[v] = (s << 12) | (unsigned int)(4095 - v);
        }
    } else {
        for (int v = tid; v < NVOX; v += 256)
            keys[v] = (counts[b * NVOX + v] << 12) | (unsigned int)(4095 - v);
    }
    {   // slotmap = 0xFF via u32 stores
        unsigned int* d32 = (unsigned int*)(slotmap + b * NVOX);
        for (int w = tid; w < NVOX / 4; w += 256) d32[w] = 0xFFFFFFFFu;
    }
    if (tid < VN) tickets[b * VN + tid] = 0u;
    if (tid == 0) ncand = 0u;
    __syncthreads();
    if (tid < 64) {
        unsigned int kr[NVOX / 64];              // 40 keys per lane (static idx)
#pragma unroll
        for (int j = 0; j < NVOX / 64; ++j) kr[j] = keys[tid + 64 * j];
        // binary search: largest T with count(keys >= T) >= 60  ->  T = K60
        unsigned int lo = 1u, hi = 0x80000000u;  // keys in [1536, 2^31)
        while (lo < hi) {
            unsigned int mid = lo + ((hi - lo + 1u) >> 1);
            int c = 0;
#pragma unroll
            for (int j = 0; j < NVOX / 64; ++j) c += (kr[j] >= mid) ? 1 : 0;
#pragma unroll
            for (int o = 32; o > 0; o >>= 1) c += __shfl_xor(c, o, 64);
            if (c >= VN) lo = mid; else hi = mid - 1u;
        }
        // collect exactly VN candidates (keys unique => count(>=K60) == 60)
#pragma unroll
        for (int j = 0; j < NVOX / 64; ++j) {
            if (kr[j] >= lo) {
                unsigned int p = atomicAdd(&ncand, 1u);
                cand[p] = kr[j];
            }
        }
        // rank + write outputs (lanes 0..59; same wave, no barrier needed)
        if (tid < VN) {
            unsigned int ki = cand[tid];
            int r = 0;
            for (int j = 0; j < VN; ++j) r += (cand[j] > ki) ? 1 : 0;
            int v = 4095 - (int)(ki & 4095u);
            topvox[b * VN + r] = v;
            topcnt[b * VN + r] = (int)(ki >> 12);
            slotmap[b * NVOX + v] = (unsigned char)r;
            int vx = v / GDYZ, rem = v % GDYZ, vy = rem / GDZ, vz = rem % GDZ;
            float c0 = __fadd_rn(__fmul_rn((float)vx, 0.4f), 0.2f);
            float c1 = __fadd_rn(__fadd_rn(-3.2f, __fmul_rn((float)vy, 0.4f)), 0.2f);
            float c2 = __fadd_rn(__fadd_rn(-2.0f, __fmul_rn((float)vz, 0.4f)), 0.2f);
            float* vl = out + OUT_VL + (b * VN + r) * 3;
            vl[0] = c0; vl[1] = c1; vl[2] = c2;
        }
    }
}

// Pass 2: for each point in a selected voxel, grab a ticket and record index.
__global__ __launch_bounds__(256) void k_build_lists(const float* __restrict__ pc,
        const unsigned short* __restrict__ vox, int useVox,
        const unsigned char* __restrict__ slotmap,
        unsigned int* __restrict__ tickets, unsigned int* __restrict__ lists) {
    __shared__ unsigned char smap[NVOX];
    int b = blockIdx.x / NCH_L;
    int ch = blockIdx.x % NCH_L;
    {
        const unsigned int* s32 = (const unsigned int*)(slotmap + b * NVOX);
        unsigned int* d32 = (unsigned int*)smap;
        for (int v = threadIdx.x; v < NVOX / 4; v += 256) d32[v] = s32[v];
    }
    __syncthreads();
    int start = ch * CHUNK_L, end = start + CHUNK_L;
    if (useVox) {
        const unsigned short* vb = vox + (size_t)b * NPTS;
        for (int i = start + threadIdx.x * 8; i < end; i += 256 * 8) {
            uint4 w = *(const uint4*)(vb + i);
            unsigned int ids[8] = {w.x & 0xFFFFu, w.x >> 16, w.y & 0xFFFFu, w.y >> 16,
                                   w.z & 0xFFFFu, w.z >> 16, w.w & 0xFFFFu, w.w >> 16};
#pragma unroll
            for (int k = 0; k < 8; ++k) {
                if (ids[k] < NVOX) {
                    unsigned char s = smap[ids[k]];
                    if (s != 0xFF) {
                        unsigned int t = atomicAdd(&tickets[b * VN + s], 1u);
                        if (t < CAP) lists[(size_t)(b * VN + s) * CAP + t] =
                                         (unsigned int)(i + k);
                    }
                }
            }
        }
    } else {
        const float* pb = pc + (size_t)b * NPTS * 3;
        for (int i = start + threadIdx.x; i < end; i += 256) {
            int id = voxid(pb[i * 3], pb[i * 3 + 1], pb[i * 3 + 2]);
            if (id < NVOX) {
                unsigned char s = smap[id];
                if (s != 0xFF) {
                    unsigned int t = atomicAdd(&tickets[b * VN + s], 1u);
                    if (t < CAP) lists[(size_t)(b * VN + s) * CAP + t] = (unsigned int)i;
                }
            }
        }
    }
}

// Pass 3 (merged): blocks [0, BN*VN) = select+gather; blocks [BN*VN, +BN) = kc.
__global__ __launch_bounds__(64) void k_select_kc(const float* __restrict__ pc,
        const float* __restrict__ kpts,
        const int* __restrict__ topvox, const int* __restrict__ topcnt,
        const unsigned int* __restrict__ lists, float* __restrict__ out) {
    __shared__ unsigned int sorted[PMAX];
    __shared__ float vl_s[VN * 3];
    __shared__ float kc_s[VN * 6];
    __shared__ float md_s[17];
    __shared__ int mi_s[17];
    int bs = blockIdx.x;
    int lane = threadIdx.x;

    if (bs >= BN * VN) {
        // ---- keypoint conditioning for batch b ----
        int b = bs - BN * VN;
        const float* vl = out + OUT_VL + b * VN * 3;
        for (int i = lane; i < VN * 3; i += 64) vl_s[i] = vl[i];
        for (int i = lane; i < VN * 6; i += 64) kc_s[i] = 0.0f;
        __syncthreads();
        if (lane < 17) {
            const float* kp = kpts + b * 17 * 3 + lane * 3;
            float a0 = kp[2], a1 = kp[0], a2 = kp[1];  // kq = kpts[:, [2,0,1]]
            float best = 1e30f;
            int bi = 0;
            for (int i = 0; i < VN; ++i) {
                float d0 = __fsub_rn(a0, vl_s[i * 3 + 0]);
                float d1 = __fsub_rn(a1, vl_s[i * 3 + 1]);
                float d2 = __fsub_rn(a2, vl_s[i * 3 + 2]);
                float sq = __fadd_rn(__fadd_rn(__fmul_rn(d0, d0), __fmul_rn(d1, d1)),
                                     __fmul_rn(d2, d2));
                float d = __fsqrt_rn(sq);
                if (d < best) { best = d; bi = i; }
            }
            md_s[lane] = best;
            mi_s[lane] = bi;
        }
        __syncthreads();
        if (lane == 0) {
            for (int j = 0; j < 17; ++j) {
                float e[6] = {KENC[j][0], KENC[j][1], KENC[j][2], KENC[j][3],
                              KENC[j][4], md_s[j]};
                float* row = kc_s + mi_s[j] * 6;
                bool z = true;
                for (int q = 0; q < 6; ++q) z = z && (row[q] == 0.0f);
                for (int q = 0; q < 6; ++q)
                    row[q] = z ? e[q] : __fmul_rn(__fadd_rn(row[q], e[q]), 0.5f);
            }
        }
        __syncthreads();
        float* kc = out + OUT_KC + b * VN * 6;
        for (int i = lane; i < VN * 6; i += 64) kc[i] = kc_s[i];
        return;
    }

    // ---- select 40 smallest indices + cyclic gather ----
    int b = bs / VN;
    int cnt = topcnt[bs];
    float* po = out + OUT_PTS + (size_t)bs * PMAX * 3;
    if (cnt == 0) {
        for (int t = lane; t < PMAX * 3; t += 64) po[t] = 0.0f;
        return;
    }
    int K = cnt < PMAX ? cnt : PMAX;
    if (cnt <= CAP) {
        const unsigned int* L = lists + (size_t)bs * CAP;
        unsigned int vals[CAP / 64];
#pragma unroll
        for (int q = 0; q < CAP / 64; ++q) {
            int e = lane + q * 64;
            vals[q] = (e < cnt) ? L[e] : 0xFFFFFFFFu;
        }
        unsigned int lastp = 0u;
        for (int r = 0; r < K; ++r) {
            unsigned int m = 0xFFFFFFFFu;
#pragma unroll
            for (int q = 0; q < CAP / 64; ++q) {
                unsigned int v = vals[q];
                if (v >= lastp && v < m) m = v;
            }
#pragma unroll
            for (int o = 32; o > 0; o >>= 1) {
                unsigned int t = __shfl_xor(m, o, 64);
                m = (t < m) ? t : m;
            }
            if (lane == 0) sorted[r] = m;
            lastp = m + 1u;
        }
    } else {
        const float* pb = pc + (size_t)b * NPTS * 3;
        int v = topvox[bs];
        int k = 0;
        for (int base = 0; base < NPTS && k < PMAX; base += 64) {
            int i = base + lane;
            int id = voxid(pb[i * 3], pb[i * 3 + 1], pb[i * 3 + 2]);
            unsigned long long mask = __ballot(id == v);
            if (id == v) {
                int rk = k + (int)__popcll(mask & ((1ull << lane) - 1ull));
                if (rk < PMAX) sorted[rk] = (unsigned int)i;
            }
            k += (int)__popcll(mask);
        }
    }
    __syncthreads();
    for (int t = lane; t < PMAX * 3; t += 64) {
        int j = t / 3, kk = t % 3;
        int jj = (cnt >= PMAX) ? j : (j % cnt);
        unsigned int idx = sorted[jj];
        po[t] = pc[((size_t)b * NPTS + idx) * 3 + kk];
    }
}

extern "C" void kernel_launch(void* const* d_in, const int* in_sizes, int n_in,
                              void* d_out, int out_size, void* d_ws, size_t ws_size,
                              hipStream_t stream) {
    const float* pc = (const float*)d_in[0];
    const float* kpts = (const float*)d_in[1];
    float* out = (float*)d_out;
    char* ws = (char*)d_ws;

    unsigned int* counts = (unsigned int*)(ws + OFF_COUNTS);
    unsigned int* tickets = (unsigned int*)(ws + OFF_TICKETS);
    int* topvox = (int*)(ws + OFF_TOPVOX);
    int* topcnt = (int*)(ws + OFF_TOPCNT);
    unsigned char* slotmap = (unsigned char*)(ws + OFF_SLOTMAP);
    unsigned int* lists = (unsigned int*)(ws + OFF_LISTS);
    unsigned short* vox = (unsigned short*)(ws + OFF_VOX);
    unsigned int* partials = (unsigned int*)(ws + OFF_PART);
    int useVox = (ws_size >= (size_t)OFF_PART) ? 1 : 0;
    int usePart = (ws_size >= (size_t)(OFF_PART + SZ_PART)) ? 1 : 0;

    if (!usePart)  // fallback only; primary path never reads counts pre-zeroed
        hipMemsetAsync(ws + OFF_COUNTS, 0, SZ_COUNTS, stream);

    hipLaunchKernelGGL(k_vox_hist, dim3(BN * NCH_H), dim3(256), 0, stream,
                       pc, counts, vox, partials, useVox, usePart);
    hipLaunchKernelGGL(k_topk, dim3(BN), dim3(256), 0, stream,
                       partials, counts, usePart, topvox, topcnt, slotmap,
                       tickets, out);
    hipLaunchKernelGGL(k_build_lists, dim3(BN * NCH_L), dim3(256), 0, stream,
                       pc, vox, useVox, slotmap, tickets, lists);
    hipLaunchKernelGGL(k_select_kc, dim3(BN * VN + BN), dim3(64), 0, stream,
                       pc, kpts, topvox, topcnt, lists, out);
}